// Round 1
// baseline (577.803 us; speedup 1.0000x reference)
//
#include <hip/hip_runtime.h>
#include <math.h>

// Problem constants (fixed by setup_inputs): x (32,32,32,512) fp32, W (512,512) fp32.
// b=32, n=w*h=1024, d=512, emb=512, lambda=1.
// Key identity: pooled = P^T (P P^T + I)^-1 1  ==  (P^T P + I)^-1 (P^T 1)
// -> per-batch 512x512 SPD solve instead of 1024x1024.

#define B    32
#define NPTS 1024
#define D    512
#define EMB  512
#define NITER 32

// ---------------------------------------------------------------- K0: g = P^T 1
__global__ __launch_bounds__(256) void colsum_kernel(const float* __restrict__ x,
                                                     float* __restrict__ g) {
    int b = blockIdx.x;
    int d = blockIdx.y * 256 + threadIdx.x;
    const float* xp = x + (size_t)b * NPTS * D + d;
    float acc = 0.f;
    #pragma unroll 4
    for (int n = 0; n < NPTS; ++n) acc += xp[(size_t)n * D];
    g[b * D + d] = acc;
}

// ---------------------------------------------------------------- K1: G = P^T P (batched SYRK, upper tiles + mirror)
#define TK 32
__global__ __launch_bounds__(256) void syrk_kernel(const float* __restrict__ x,
                                                   float* __restrict__ G) {
    int bt = blockIdx.x;
    int b = bt / 36;
    int t = bt % 36;
    // map t -> (i,j), i<=j over 8x8 tile grid (row i has 8-i tiles)
    int i = 0, rem = t;
    #pragma unroll
    for (int ii = 0; ii < 8; ++ii) {
        int c = 8 - ii;
        if (rem < c) { i = ii; break; }
        rem -= c;
    }
    int j = i + rem;
    int i0 = i * 64, j0 = j * 64;

    const float* P = x + (size_t)b * NPTS * D;
    __shared__ float At[TK][64];
    __shared__ float Bt[TK][64];

    int tid = threadIdx.x;
    int lc = tid & 63;     // load col 0..63
    int lr = tid >> 6;     // load row group 0..3
    int ti = (tid & 15) * 4;
    int tj = (tid >> 4) * 4;

    float acc[4][4] = {{0.f}};

    for (int k0 = 0; k0 < NPTS; k0 += TK) {
        #pragma unroll
        for (int rr = 0; rr < TK; rr += 4) {
            int row = rr + lr;
            int base = (k0 + row) * D;
            At[row][lc] = P[base + i0 + lc];
            Bt[row][lc] = P[base + j0 + lc];
        }
        __syncthreads();
        #pragma unroll
        for (int kk = 0; kk < TK; ++kk) {
            float a0 = At[kk][ti + 0], a1 = At[kk][ti + 1],
                  a2 = At[kk][ti + 2], a3 = At[kk][ti + 3];
            float b0 = Bt[kk][tj + 0], b1 = Bt[kk][tj + 1],
                  b2 = Bt[kk][tj + 2], b3 = Bt[kk][tj + 3];
            acc[0][0] = fmaf(a0, b0, acc[0][0]); acc[0][1] = fmaf(a0, b1, acc[0][1]);
            acc[0][2] = fmaf(a0, b2, acc[0][2]); acc[0][3] = fmaf(a0, b3, acc[0][3]);
            acc[1][0] = fmaf(a1, b0, acc[1][0]); acc[1][1] = fmaf(a1, b1, acc[1][1]);
            acc[1][2] = fmaf(a1, b2, acc[1][2]); acc[1][3] = fmaf(a1, b3, acc[1][3]);
            acc[2][0] = fmaf(a2, b0, acc[2][0]); acc[2][1] = fmaf(a2, b1, acc[2][1]);
            acc[2][2] = fmaf(a2, b2, acc[2][2]); acc[2][3] = fmaf(a2, b3, acc[2][3]);
            acc[3][0] = fmaf(a3, b0, acc[3][0]); acc[3][1] = fmaf(a3, b1, acc[3][1]);
            acc[3][2] = fmaf(a3, b2, acc[3][2]); acc[3][3] = fmaf(a3, b3, acc[3][3]);
        }
        __syncthreads();
    }

    float* Gb = G + (size_t)b * D * D;
    #pragma unroll
    for (int u = 0; u < 4; ++u)
        #pragma unroll
        for (int v = 0; v < 4; ++v)
            Gb[(i0 + ti + u) * D + (j0 + tj + v)] = acc[u][v];
    if (i != j) {
        #pragma unroll
        for (int u = 0; u < 4; ++u)
            #pragma unroll
            for (int v = 0; v < 4; ++v)
                Gb[(j0 + tj + v) * D + (i0 + ti + u)] = acc[u][v];
    }
}

// ---------------------------------------------------------------- K2: CG solve (G + I) pooled = g, one WG per batch
__device__ __forceinline__ float block_reduce(float v, float* red, int nwaves) {
    #pragma unroll
    for (int o = 32; o > 0; o >>= 1) v += __shfl_down(v, o);
    int wid  = threadIdx.x >> 6;
    int lane = threadIdx.x & 63;
    __syncthreads();                 // protect red from previous use
    if (lane == 0) red[wid] = v;
    __syncthreads();
    float s = 0.f;
    if ((int)threadIdx.x < nwaves) s = red[threadIdx.x];
    if ((int)threadIdx.x < nwaves) {
        #pragma unroll
        for (int o = 8; o > 0; o >>= 1) s += __shfl_down(s, o);
    }
    return s;   // valid in thread 0
}

__global__ __launch_bounds__(1024) void cg_kernel(const float* __restrict__ G,
                                                  const float* __restrict__ gvec,
                                                  float* __restrict__ pooled) {
    int b = blockIdx.x;
    const float* Gb = G + (size_t)b * D * D;

    __shared__ float xv[D], rv[D], pv[D], yv[D];
    __shared__ float part[1024];
    __shared__ float red[16];
    __shared__ float sAlpha, sBeta, sRR;

    int t = threadIdx.x;
    int e = t & (D - 1);
    int half = t >> 9;          // 0 or 1

    if (half == 0) {
        float ge = gvec[b * D + t];
        xv[t] = 0.f; rv[t] = ge; pv[t] = ge;
    }
    __syncthreads();

    float v0 = (half == 0) ? rv[t] * rv[t] : 0.f;
    float rr0 = block_reduce(v0, red, 16);
    if (t == 0) sRR = rr0;
    __syncthreads();
    float rr = sRR;

    for (int it = 0; it < NITER; ++it) {
        // ---- y = (G + I) p : thread t handles output e over half the c-range
        const float* col = Gb + (half << 8) * D + e;   // G[c][e], c in [half*256, half*256+256)
        const float* pvh = pv + (half << 8);
        float acc = 0.f;
        #pragma unroll 8
        for (int c = 0; c < 256; ++c)
            acc = fmaf(pvh[c], col[c * D], acc);
        part[t] = acc;
        __syncthreads();
        if (half == 0) yv[t] = part[t] + part[t + D] + pv[t];
        __syncthreads();

        // ---- alpha = rr / (p.y)
        float pyv = (half == 0) ? pv[t] * yv[t] : 0.f;
        float py = block_reduce(pyv, red, 16);
        if (t == 0) sAlpha = rr / fmaxf(py, 1e-30f);
        __syncthreads();
        float alpha = sAlpha;

        // ---- x += a p ; r -= a y ; rr_new
        float rn2 = 0.f;
        if (half == 0) {
            xv[t] += alpha * pv[t];
            float rn = rv[t] - alpha * yv[t];
            rv[t] = rn;
            rn2 = rn * rn;
        }
        float rrn = block_reduce(rn2, red, 16);
        if (t == 0) { sBeta = rrn / fmaxf(rr, 1e-30f); sRR = rrn; }
        __syncthreads();
        float beta = sBeta;
        rr = sRR;
        if (half == 0) pv[t] = rv[t] + beta * pv[t];
        __syncthreads();
    }

    if (half == 0) pooled[b * D + t] = xv[t];
}

// ---------------------------------------------------------------- K3: out = l2norm(pooled @ W)
__global__ __launch_bounds__(512) void outproj_kernel(const float* __restrict__ pooled,
                                                      const float* __restrict__ W,
                                                      float* __restrict__ out) {
    int b = blockIdx.x;
    __shared__ float pl[D];
    __shared__ float red[8];
    __shared__ float sNorm;
    int t = threadIdx.x;

    pl[t] = pooled[b * D + t];
    __syncthreads();

    float acc = 0.f;
    #pragma unroll 8
    for (int dd = 0; dd < D; ++dd)
        acc = fmaf(pl[dd], W[dd * EMB + t], acc);

    float ss = block_reduce(acc * acc, red, 8);
    if (t == 0) sNorm = rsqrtf(fmaxf(ss, 1e-12f));
    __syncthreads();
    out[b * EMB + t] = acc * sNorm;
}

// ---------------------------------------------------------------- launch
extern "C" void kernel_launch(void* const* d_in, const int* in_sizes, int n_in,
                              void* d_out, int out_size, void* d_ws, size_t ws_size,
                              hipStream_t stream) {
    const float* x = (const float*)d_in[0];   // (32,1024,512)
    const float* W = (const float*)d_in[1];   // (512,512)
    float* out = (float*)d_out;               // (32,512)

    float* ws = (float*)d_ws;
    float* G      = ws;                               // 32*512*512 = 8,388,608 floats (32 MB)
    float* gvec   = ws + (size_t)B * D * D;           // 32*512
    float* pooled = gvec + (size_t)B * D;             // 32*512

    colsum_kernel<<<dim3(B, D / 256), 256, 0, stream>>>(x, gvec);
    syrk_kernel<<<dim3(B * 36), 256, 0, stream>>>(x, G);
    cg_kernel<<<dim3(B), 1024, 0, stream>>>(G, gvec, pooled);
    outproj_kernel<<<dim3(B), 512, 0, stream>>>(pooled, W, out);
}

// Round 2
// 408.519 us; speedup vs baseline: 1.4144x; 1.4144x over previous
//
#include <hip/hip_runtime.h>
#include <math.h>
#include <stdint.h>

// x (32,32,32,512) fp32, W (512,512) fp32. b=32, n=1024, d=512, emb=512, lambda=1.
// pooled = (P^T P + I)^-1 (P^T 1)  [push-through identity, verified round 1]
// Round 2: G = P^T P via bf16x3 MFMA on Q = P^T (hi/lo split), CG matvec float4.

#define B    32
#define NPTS 1024
#define D    512
#define EMB  512
#define NITER 32

typedef __attribute__((ext_vector_type(8))) short short8;
typedef __attribute__((ext_vector_type(4))) float f32x4;

#define MFMA16(a, b, c) __builtin_amdgcn_mfma_f32_16x16x32_bf16(a, b, c, 0, 0, 0)

__device__ __forceinline__ void gload16(const void* g, void* lds_wave_base) {
    __builtin_amdgcn_global_load_lds(
        (const __attribute__((address_space(1))) void*)g,
        (__attribute__((address_space(3))) void*)lds_wave_base, 16, 0, 0);
}

// ---------------------------------------------------------------- prep: x(b,n,d) -> Qh,Ql (b,d,n) bf16 hi/lo
__global__ __launch_bounds__(256) void prep_kernel(const float* __restrict__ x,
                                                   short* __restrict__ Qh,
                                                   short* __restrict__ Ql) {
    int n0 = blockIdx.x * 64, d0 = blockIdx.y * 64, bl = blockIdx.z;
    const float* xb = x + (size_t)bl * NPTS * D;
    __shared__ float tile[64][65];
    int t = threadIdx.x;
    int lrow = t >> 4, lc4 = (t & 15) * 4;
    #pragma unroll
    for (int r = 0; r < 4; ++r) {
        int row = lrow + r * 16;
        const float* src = xb + (size_t)(n0 + row) * D + d0 + lc4;
        tile[row][lc4 + 0] = src[0];
        tile[row][lc4 + 1] = src[1];
        tile[row][lc4 + 2] = src[2];
        tile[row][lc4 + 3] = src[3];
    }
    __syncthreads();
    int drow = t >> 2, nseg = (t & 3) * 16;
    size_t obase = (size_t)bl * D * NPTS + (size_t)(d0 + drow) * NPTS + n0 + nseg;
    short8 h0, h1, l0, l1;
    #pragma unroll
    for (int k = 0; k < 8; ++k) {
        float v = tile[nseg + k][drow];
        uint32_t u = __float_as_uint(v);
        uint32_t hb = (u + 0x7fffu + ((u >> 16) & 1u)) & 0xffff0000u;
        float hf = __uint_as_float(hb);
        float lf = v - hf;                                   // exact
        uint32_t ul = __float_as_uint(lf);
        uint32_t lb = (ul + 0x7fffu + ((ul >> 16) & 1u)) >> 16;
        h0[k] = (short)(hb >> 16);
        l0[k] = (short)lb;
    }
    #pragma unroll
    for (int k = 0; k < 8; ++k) {
        float v = tile[nseg + 8 + k][drow];
        uint32_t u = __float_as_uint(v);
        uint32_t hb = (u + 0x7fffu + ((u >> 16) & 1u)) & 0xffff0000u;
        float hf = __uint_as_float(hb);
        float lf = v - hf;
        uint32_t ul = __float_as_uint(lf);
        uint32_t lb = (ul + 0x7fffu + ((ul >> 16) & 1u)) >> 16;
        h1[k] = (short)(hb >> 16);
        l1[k] = (short)lb;
    }
    *(short8*)(Qh + obase)     = h0;
    *(short8*)(Qh + obase + 8) = h1;
    *(short8*)(Ql + obase)     = l0;
    *(short8*)(Ql + obase + 8) = l1;
}

// ---------------------------------------------------------------- colsum: g = P^T 1 (fp32, exact path)
__global__ __launch_bounds__(256) void colsum_kernel(const float* __restrict__ x,
                                                     float* __restrict__ g) {
    int b = blockIdx.x, dt = blockIdx.y;
    int t = threadIdx.x;
    int d = dt * 64 + (t & 63);
    int ng = t >> 6;
    const float* xp = x + (size_t)b * NPTS * D + (size_t)ng * 256 * D + d;
    float acc = 0.f;
    #pragma unroll 8
    for (int n = 0; n < 256; ++n) acc += xp[(size_t)n * D];
    __shared__ float prt[4][64];
    prt[ng][t & 63] = acc;
    __syncthreads();
    if (t < 64) g[b * D + dt * 64 + t] = prt[0][t] + prt[1][t] + prt[2][t] + prt[3][t];
}

// ---------------------------------------------------------------- syrk: G = Q Q^T, bf16x3 MFMA, 128x128 tile
__global__ __launch_bounds__(256) void syrk_kernel(const short* __restrict__ Qh,
                                                   const short* __restrict__ Ql,
                                                   float* __restrict__ G) {
    int bx = blockIdx.x, bl = blockIdx.y;
    int i0 = (bx >> 2) * 128, j0 = (bx & 3) * 128;
    const short* Qhb = Qh + (size_t)bl * D * NPTS;
    const short* Qlb = Ql + (size_t)bl * D * NPTS;
    float* Gb = G + (size_t)bl * D * D;

    __shared__ short smem[4 * 4096];   // Ah, Al, Bh, Bl: [128][32] bf16 each (8KB)
    char* smb = (char*)smem;

    int t = threadIdx.x;
    int lane = t & 63, wid = t >> 6;
    int wm = wid >> 1, wn = wid & 1;

    f32x4 acc[4][4];
    f32x4 zero = {0.f, 0.f, 0.f, 0.f};
    #pragma unroll
    for (int a = 0; a < 4; ++a)
        #pragma unroll
        for (int c = 0; c < 4; ++c) acc[a][c] = zero;

    for (int kt = 0; kt < NPTS / 32; ++kt) {
        int ks = kt * 32;
        #pragma unroll
        for (int q = 0; q < 2; ++q) {
            int off = q * 4096 + wid * 1024 + lane * 16;   // byte offset in 8KB tile
            int row = off >> 6, inb = off & 63;
            int ldsoff = q * 4096 + wid * 1024;            // wave-uniform
            const char* sAh = (const char*)(Qhb + (size_t)(i0 + row) * NPTS + ks) + inb;
            const char* sAl = (const char*)(Qlb + (size_t)(i0 + row) * NPTS + ks) + inb;
            const char* sBh = (const char*)(Qhb + (size_t)(j0 + row) * NPTS + ks) + inb;
            const char* sBl = (const char*)(Qlb + (size_t)(j0 + row) * NPTS + ks) + inb;
            gload16(sAh, smb + ldsoff);
            gload16(sAl, smb + 8192  + ldsoff);
            gload16(sBh, smb + 16384 + ldsoff);
            gload16(sBl, smb + 24576 + ldsoff);
        }
        __syncthreads();

        short8 ah[4], al[4], bh[4], bl2[4];
        int mrow = lane & 15;
        int kb = (lane >> 4) * 8;                         // shorts
        #pragma unroll
        for (int f = 0; f < 4; ++f) {
            int ra = (wm * 64 + f * 16 + mrow) * 32 + kb;
            int rb = (wn * 64 + f * 16 + mrow) * 32 + kb;
            ah[f]  = *(const short8*)(smem + ra);
            al[f]  = *(const short8*)(smem + 4096 + ra);
            bh[f]  = *(const short8*)(smem + 8192 + rb);
            bl2[f] = *(const short8*)(smem + 12288 + rb);
        }
        #pragma unroll
        for (int fm = 0; fm < 4; ++fm)
            #pragma unroll
            for (int fn = 0; fn < 4; ++fn)
                acc[fm][fn] = MFMA16(ah[fm], bh[fn], acc[fm][fn]);
        #pragma unroll
        for (int fm = 0; fm < 4; ++fm)
            #pragma unroll
            for (int fn = 0; fn < 4; ++fn)
                acc[fm][fn] = MFMA16(ah[fm], bl2[fn], acc[fm][fn]);
        #pragma unroll
        for (int fm = 0; fm < 4; ++fm)
            #pragma unroll
            for (int fn = 0; fn < 4; ++fn)
                acc[fm][fn] = MFMA16(al[fm], bh[fn], acc[fm][fn]);
        __syncthreads();
    }

    // C/D layout (verified): col = lane&15, row = (lane>>4)*4 + reg
    int crow0 = i0 + wm * 64 + (lane >> 4) * 4;
    int ccol0 = j0 + wn * 64 + (lane & 15);
    #pragma unroll
    for (int fm = 0; fm < 4; ++fm)
        #pragma unroll
        for (int fn = 0; fn < 4; ++fn)
            #pragma unroll
            for (int r = 0; r < 4; ++r)
                Gb[(size_t)(crow0 + fm * 16 + r) * D + (ccol0 + fn * 16)] = acc[fm][fn][r];
}

// ---------------------------------------------------------------- CG solve (G+I) pooled = g
__device__ __forceinline__ float block_reduce(float v, float* red, int nwaves) {
    #pragma unroll
    for (int o = 32; o > 0; o >>= 1) v += __shfl_down(v, o);
    int wid = threadIdx.x >> 6, lane = threadIdx.x & 63;
    __syncthreads();
    if (lane == 0) red[wid] = v;
    __syncthreads();
    float s = 0.f;
    if ((int)threadIdx.x < nwaves) {
        s = red[threadIdx.x];
        #pragma unroll
        for (int o = 8; o > 0; o >>= 1) s += __shfl_down(s, o);
    }
    return s;   // valid in thread 0
}

__global__ __launch_bounds__(1024) void cg_kernel(const float* __restrict__ G,
                                                  const float* __restrict__ gvec,
                                                  float* __restrict__ pooled) {
    int b = blockIdx.x;
    const float* Gb = G + (size_t)b * D * D;

    __shared__ float partf[4096];          // 16 KB
    __shared__ float xv[D], rv[D], pv[D], yv[D];
    __shared__ float red[16];
    __shared__ float sAlpha, sBeta, sRR;

    int t = threadIdx.x;
    float ge = (t < D) ? gvec[b * D + t] : 0.f;
    if (t < D) { xv[t] = 0.f; rv[t] = ge; pv[t] = ge; }

    float rr0 = block_reduce(ge * ge, red, 16);
    if (t == 0) sRR = rr0;
    __syncthreads();
    float rr = sRR;

    int ec = (t & 127) * 4;
    int c0 = (t >> 7) * 64;
    const float* gp = Gb + (size_t)c0 * D + ec;

    for (int it = 0; it < NITER; ++it) {
        // y = (G+I)p : 1024 threads, 4 outputs x 1/8 of c-range each
        f32x4 acc = {0.f, 0.f, 0.f, 0.f};
        #pragma unroll 16
        for (int c = 0; c < 64; ++c) {
            float pc = pv[c0 + c];
            f32x4 q = *(const f32x4*)(gp + (size_t)c * D);
            acc.x = fmaf(q.x, pc, acc.x);
            acc.y = fmaf(q.y, pc, acc.y);
            acc.z = fmaf(q.z, pc, acc.z);
            acc.w = fmaf(q.w, pc, acc.w);
        }
        *(f32x4*)(partf + t * 4) = acc;
        __syncthreads();

        float pyp = 0.f;
        if (t < D) {
            float y = pv[t];
            #pragma unroll
            for (int w = 0; w < 8; ++w) y += partf[t + 512 * w];
            yv[t] = y;
            pyp = pv[t] * y;
        }
        float py = block_reduce(pyp, red, 16);
        if (t == 0) sAlpha = rr / fmaxf(py, 1e-30f);
        __syncthreads();
        float alpha = sAlpha;

        float rn2 = 0.f;
        if (t < D) {
            xv[t] += alpha * pv[t];
            float rn = rv[t] - alpha * yv[t];
            rv[t] = rn;
            rn2 = rn * rn;
        }
        float rrn = block_reduce(rn2, red, 16);
        if (t == 0) { sBeta = rrn / fmaxf(rr, 1e-30f); sRR = rrn; }
        __syncthreads();
        float beta = sBeta;
        rr = sRR;
        if (t < D) pv[t] = rv[t] + beta * pv[t];
        __syncthreads();
    }

    if (t < D) pooled[b * D + t] = xv[t];
}

// ---------------------------------------------------------------- outproj: out = l2norm(pooled @ W)
__global__ __launch_bounds__(512) void outproj_kernel(const float* __restrict__ pooled,
                                                      const float* __restrict__ W,
                                                      float* __restrict__ out) {
    int b = blockIdx.x;
    __shared__ float pl[D];
    __shared__ float red[8];
    __shared__ float sNorm;
    int t = threadIdx.x;
    pl[t] = pooled[b * D + t];
    __syncthreads();
    float acc = 0.f;
    #pragma unroll 8
    for (int dd = 0; dd < D; ++dd) acc = fmaf(pl[dd], W[dd * EMB + t], acc);
    float ss = block_reduce(acc * acc, red, 8);
    if (t == 0) sNorm = rsqrtf(fmaxf(ss, 1e-12f));
    __syncthreads();
    out[b * EMB + t] = acc * sNorm;
}

// ---------------------------------------------------------------- launch
extern "C" void kernel_launch(void* const* d_in, const int* in_sizes, int n_in,
                              void* d_out, int out_size, void* d_ws, size_t ws_size,
                              hipStream_t stream) {
    const float* x = (const float*)d_in[0];
    const float* W = (const float*)d_in[1];
    float* out = (float*)d_out;

    char* ws = (char*)d_ws;
    float* G = (float*)ws;                                     // 32 MB
    size_t goff = (size_t)B * D * D * sizeof(float);
    float* gvec   = (float*)(ws + goff);
    float* pooled = (float*)(ws + goff + (size_t)B * D * sizeof(float));
    size_t qoff = goff + 2 * (size_t)B * D * sizeof(float);
    qoff = (qoff + 255) & ~(size_t)255;

    size_t per_batch_q = (size_t)D * NPTS * sizeof(short);     // 1 MB
    size_t avail = ws_size > qoff ? ws_size - qoff : 0;
    int CH = (int)(avail / (2 * per_batch_q));
    if (CH > B) CH = B;
    if (CH < 1) CH = 1;
    short* Qh = (short*)(ws + qoff);
    short* Ql = (short*)(ws + qoff + (size_t)CH * per_batch_q);

    colsum_kernel<<<dim3(B, 8), 256, 0, stream>>>(x, gvec);
    for (int c0 = 0; c0 < B; c0 += CH) {
        int nb = (B - c0 < CH) ? (B - c0) : CH;
        prep_kernel<<<dim3(16, 8, nb), 256, 0, stream>>>(x + (size_t)c0 * NPTS * D, Qh, Ql);
        syrk_kernel<<<dim3(16, nb), 256, 0, stream>>>(Qh, Ql, G + (size_t)c0 * D * D);
    }
    cg_kernel<<<dim3(B), 1024, 0, stream>>>(G, gvec, pooled);
    outproj_kernel<<<dim3(B), 512, 0, stream>>>(pooled, W, out);
}

// Round 3
// 218.542 us; speedup vs baseline: 2.6439x; 1.8693x over previous
//
#include <hip/hip_runtime.h>
#include <math.h>
#include <stdint.h>

// x (32,32,32,512) fp32, W (512,512) fp32. b=32, n=1024, d=512, emb=512, lambda=1.
// pooled = (P^T P + I)^-1 (P^T 1)  [push-through identity, verified round 1]
// Round 3: G stored fp16 (cg reads half the bytes), NITER 20, symmetric syrk
// (10/16 tiles + mirror), colsum fused into prep.

#define B    32
#define NPTS 1024
#define D    512
#define EMB  512
#define NITER 20

typedef __attribute__((ext_vector_type(8))) short short8;
typedef __attribute__((ext_vector_type(4))) float f32x4;
typedef __attribute__((ext_vector_type(8))) _Float16 h16x8;
typedef __attribute__((ext_vector_type(4))) _Float16 h16x4;

#define MFMA16(a, b, c) __builtin_amdgcn_mfma_f32_16x16x32_bf16(a, b, c, 0, 0, 0)

__device__ __forceinline__ void gload16(const void* g, void* lds_wave_base) {
    __builtin_amdgcn_global_load_lds(
        (const __attribute__((address_space(1))) void*)g,
        (__attribute__((address_space(3))) void*)lds_wave_base, 16, 0, 0);
}

// ---------------------------------------------------------------- prep: x(b,n,d) -> Qh,Ql (b,d,n) bf16 hi/lo + colsum partials
__global__ __launch_bounds__(256) void prep_kernel(const float* __restrict__ x,
                                                   short* __restrict__ Qh,
                                                   short* __restrict__ Ql,
                                                   float* __restrict__ psum,
                                                   int b0) {
    int n0 = blockIdx.x * 64, d0 = blockIdx.y * 64, bl = blockIdx.z;
    const float* xb = x + (size_t)bl * NPTS * D;
    __shared__ float tile[64][65];
    __shared__ float cs[4][64];
    int t = threadIdx.x;
    int lrow = t >> 4, lc4 = (t & 15) * 4;
    #pragma unroll
    for (int r = 0; r < 4; ++r) {
        int row = lrow + r * 16;
        const float* src = xb + (size_t)(n0 + row) * D + d0 + lc4;
        tile[row][lc4 + 0] = src[0];
        tile[row][lc4 + 1] = src[1];
        tile[row][lc4 + 2] = src[2];
        tile[row][lc4 + 3] = src[3];
    }
    __syncthreads();

    // column partial sums (colsum fusion)
    {
        int col = t & 63, grp = t >> 6;
        float s = 0.f;
        #pragma unroll
        for (int r = 0; r < 16; ++r) s += tile[grp * 16 + r][col];
        cs[grp][col] = s;
    }
    __syncthreads();
    if (t < 64)
        psum[((size_t)(b0 + bl) * 16 + blockIdx.x) * D + d0 + t] =
            cs[0][t] + cs[1][t] + cs[2][t] + cs[3][t];

    // transposed hi/lo bf16 pack
    int drow = t >> 2, nseg = (t & 3) * 16;
    size_t obase = (size_t)bl * D * NPTS + (size_t)(d0 + drow) * NPTS + n0 + nseg;
    short8 h0, h1, l0, l1;
    #pragma unroll
    for (int k = 0; k < 8; ++k) {
        float v = tile[nseg + k][drow];
        uint32_t u = __float_as_uint(v);
        uint32_t hb = (u + 0x7fffu + ((u >> 16) & 1u)) & 0xffff0000u;
        float lf = v - __uint_as_float(hb);                   // exact
        uint32_t ul = __float_as_uint(lf);
        uint32_t lb = (ul + 0x7fffu + ((ul >> 16) & 1u)) >> 16;
        h0[k] = (short)(hb >> 16);
        l0[k] = (short)lb;
    }
    #pragma unroll
    for (int k = 0; k < 8; ++k) {
        float v = tile[nseg + 8 + k][drow];
        uint32_t u = __float_as_uint(v);
        uint32_t hb = (u + 0x7fffu + ((u >> 16) & 1u)) & 0xffff0000u;
        float lf = v - __uint_as_float(hb);
        uint32_t ul = __float_as_uint(lf);
        uint32_t lb = (ul + 0x7fffu + ((ul >> 16) & 1u)) >> 16;
        h1[k] = (short)(hb >> 16);
        l1[k] = (short)lb;
    }
    *(short8*)(Qh + obase)     = h0;
    *(short8*)(Qh + obase + 8) = h1;
    *(short8*)(Ql + obase)     = l0;
    *(short8*)(Ql + obase + 8) = l1;
}

// ---------------------------------------------------------------- colsum reduce: gvec = sum over 16 n-tiles
__global__ __launch_bounds__(256) void colsum_reduce(const float* __restrict__ psum,
                                                     float* __restrict__ gvec) {
    int b = blockIdx.x, t = threadIdx.x;
    for (int dd = t; dd < D; dd += 256) {
        float s = 0.f;
        #pragma unroll
        for (int i = 0; i < 16; ++i) s += psum[((size_t)b * 16 + i) * D + dd];
        gvec[b * D + dd] = s;
    }
}

// ---------------------------------------------------------------- syrk: G = Q Q^T (bf16x3 MFMA), upper 128x128 tiles + mirror, fp16 out
__global__ __launch_bounds__(256) void syrk_kernel(const short* __restrict__ Qh,
                                                   const short* __restrict__ Ql,
                                                   _Float16* __restrict__ G) {
    int bx = blockIdx.x, bl = blockIdx.y;
    int i = 0, rem = bx;
    #pragma unroll
    for (int ii = 0; ii < 4; ++ii) {
        int c = 4 - ii;
        if (rem < c) { i = ii; break; }
        rem -= c;
    }
    int j = i + rem;
    int i0 = i * 128, j0 = j * 128;

    const short* Qhb = Qh + (size_t)bl * D * NPTS;
    const short* Qlb = Ql + (size_t)bl * D * NPTS;
    _Float16* Gb = G + (size_t)bl * D * D;

    __shared__ short smem[4 * 4096];   // Ah, Al, Bh, Bl: [128][32] bf16 each
    char* smb = (char*)smem;

    int t = threadIdx.x;
    int lane = t & 63, wid = t >> 6;
    int wm = wid >> 1, wn = wid & 1;

    f32x4 acc[4][4];
    f32x4 zero = {0.f, 0.f, 0.f, 0.f};
    #pragma unroll
    for (int a = 0; a < 4; ++a)
        #pragma unroll
        for (int c = 0; c < 4; ++c) acc[a][c] = zero;

    for (int kt = 0; kt < NPTS / 32; ++kt) {
        int ks = kt * 32;
        #pragma unroll
        for (int q = 0; q < 2; ++q) {
            int off = q * 4096 + wid * 1024 + lane * 16;
            int row = off >> 6, inb = off & 63;
            int ldsoff = q * 4096 + wid * 1024;            // wave-uniform
            const char* sAh = (const char*)(Qhb + (size_t)(i0 + row) * NPTS + ks) + inb;
            const char* sAl = (const char*)(Qlb + (size_t)(i0 + row) * NPTS + ks) + inb;
            const char* sBh = (const char*)(Qhb + (size_t)(j0 + row) * NPTS + ks) + inb;
            const char* sBl = (const char*)(Qlb + (size_t)(j0 + row) * NPTS + ks) + inb;
            gload16(sAh, smb + ldsoff);
            gload16(sAl, smb + 8192  + ldsoff);
            gload16(sBh, smb + 16384 + ldsoff);
            gload16(sBl, smb + 24576 + ldsoff);
        }
        __syncthreads();

        short8 ah[4], al[4], bh[4], bl2[4];
        int mrow = lane & 15;
        int kb = (lane >> 4) * 8;
        #pragma unroll
        for (int f = 0; f < 4; ++f) {
            int ra = (wm * 64 + f * 16 + mrow) * 32 + kb;
            int rb = (wn * 64 + f * 16 + mrow) * 32 + kb;
            ah[f]  = *(const short8*)(smem + ra);
            al[f]  = *(const short8*)(smem + 4096 + ra);
            bh[f]  = *(const short8*)(smem + 8192 + rb);
            bl2[f] = *(const short8*)(smem + 12288 + rb);
        }
        #pragma unroll
        for (int fm = 0; fm < 4; ++fm)
            #pragma unroll
            for (int fn = 0; fn < 4; ++fn)
                acc[fm][fn] = MFMA16(ah[fm], bh[fn], acc[fm][fn]);
        #pragma unroll
        for (int fm = 0; fm < 4; ++fm)
            #pragma unroll
            for (int fn = 0; fn < 4; ++fn)
                acc[fm][fn] = MFMA16(ah[fm], bl2[fn], acc[fm][fn]);
        #pragma unroll
        for (int fm = 0; fm < 4; ++fm)
            #pragma unroll
            for (int fn = 0; fn < 4; ++fn)
                acc[fm][fn] = MFMA16(al[fm], bh[fn], acc[fm][fn]);
        __syncthreads();
    }

    // C/D layout: col = lane&15, row = (lane>>4)*4 + reg
    int crow0 = i0 + wm * 64 + (lane >> 4) * 4;
    int ccol0 = j0 + wn * 64 + (lane & 15);
    #pragma unroll
    for (int fm = 0; fm < 4; ++fm)
        #pragma unroll
        for (int fn = 0; fn < 4; ++fn)
            #pragma unroll
            for (int r = 0; r < 4; ++r)
                Gb[(size_t)(crow0 + fm * 16 + r) * D + (ccol0 + fn * 16)] =
                    (_Float16)acc[fm][fn][r];
    if (i != j) {
        #pragma unroll
        for (int fm = 0; fm < 4; ++fm)
            #pragma unroll
            for (int fn = 0; fn < 4; ++fn) {
                h16x4 v = {(_Float16)acc[fm][fn][0], (_Float16)acc[fm][fn][1],
                           (_Float16)acc[fm][fn][2], (_Float16)acc[fm][fn][3]};
                *(h16x4*)&Gb[(size_t)(ccol0 + fn * 16) * D + (crow0 + fm * 16)] = v;
            }
    }
}

// ---------------------------------------------------------------- CG solve (G+I) pooled = g, fp16 G
__device__ __forceinline__ float block_reduce(float v, float* red, int nwaves) {
    #pragma unroll
    for (int o = 32; o > 0; o >>= 1) v += __shfl_down(v, o);
    int wid = threadIdx.x >> 6, lane = threadIdx.x & 63;
    __syncthreads();
    if (lane == 0) red[wid] = v;
    __syncthreads();
    float s = 0.f;
    if ((int)threadIdx.x < nwaves) {
        s = red[threadIdx.x];
        #pragma unroll
        for (int o = 8; o > 0; o >>= 1) s += __shfl_down(s, o);
    }
    return s;   // valid in thread 0
}

__global__ __launch_bounds__(1024) void cg_kernel(const _Float16* __restrict__ G,
                                                  const float* __restrict__ gvec,
                                                  float* __restrict__ pooled) {
    int b = blockIdx.x;
    const _Float16* Gb = G + (size_t)b * D * D;

    __shared__ float partf[16 * 512];      // 32 KB
    __shared__ float xv[D], rv[D], pv[D], yv[D];
    __shared__ float red[16];
    __shared__ float sAlpha, sBeta, sRR;

    int t = threadIdx.x;
    float ge = (t < D) ? gvec[b * D + t] : 0.f;
    if (t < D) { xv[t] = 0.f; rv[t] = ge; pv[t] = ge; }

    float rr0 = block_reduce(ge * ge, red, 16);
    if (t == 0) sRR = rr0;
    __syncthreads();
    float rr = sRR;

    int ecol = (t & 63) * 8;               // 8 outputs per thread
    int cgrp = t >> 6;                     // 16 c-groups of 32
    const _Float16* gp = Gb + (size_t)(cgrp * 32) * D + ecol;

    for (int it = 0; it < NITER; ++it) {
        // y = (G+I)p
        float acc[8] = {0.f, 0.f, 0.f, 0.f, 0.f, 0.f, 0.f, 0.f};
        #pragma unroll 8
        for (int c = 0; c < 32; ++c) {
            float pc = pv[cgrp * 32 + c];
            h16x8 q = *(const h16x8*)(gp + (size_t)c * D);
            #pragma unroll
            for (int k = 0; k < 8; ++k)
                acc[k] = fmaf((float)q[k], pc, acc[k]);
        }
        f32x4 a0 = {acc[0], acc[1], acc[2], acc[3]};
        f32x4 a1 = {acc[4], acc[5], acc[6], acc[7]};
        *(f32x4*)(partf + cgrp * 512 + ecol)     = a0;
        *(f32x4*)(partf + cgrp * 512 + ecol + 4) = a1;
        __syncthreads();

        float pyp = 0.f;
        if (t < D) {
            float y = pv[t];
            #pragma unroll
            for (int g = 0; g < 16; ++g) y += partf[g * 512 + t];
            yv[t] = y;
            pyp = pv[t] * y;
        }
        float py = block_reduce(pyp, red, 16);
        if (t == 0) sAlpha = rr / fmaxf(py, 1e-30f);
        __syncthreads();
        float alpha = sAlpha;

        float rn2 = 0.f;
        if (t < D) {
            xv[t] += alpha * pv[t];
            float rn = rv[t] - alpha * yv[t];
            rv[t] = rn;
            rn2 = rn * rn;
        }
        float rrn = block_reduce(rn2, red, 16);
        if (t == 0) { sBeta = rrn / fmaxf(rr, 1e-30f); sRR = rrn; }
        __syncthreads();
        float beta = sBeta;
        rr = sRR;
        if (t < D) pv[t] = rv[t] + beta * pv[t];
        __syncthreads();
    }

    if (t < D) pooled[b * D + t] = xv[t];
}

// ---------------------------------------------------------------- outproj: out = l2norm(pooled @ W)
__global__ __launch_bounds__(512) void outproj_kernel(const float* __restrict__ pooled,
                                                      const float* __restrict__ W,
                                                      float* __restrict__ out) {
    int b = blockIdx.x;
    __shared__ float pl[D];
    __shared__ float red[8];
    __shared__ float sNorm;
    int t = threadIdx.x;
    pl[t] = pooled[b * D + t];
    __syncthreads();
    float acc = 0.f;
    #pragma unroll 8
    for (int dd = 0; dd < D; ++dd) acc = fmaf(pl[dd], W[dd * EMB + t], acc);
    float ss = block_reduce(acc * acc, red, 8);
    if (t == 0) sNorm = rsqrtf(fmaxf(ss, 1e-12f));
    __syncthreads();
    out[b * EMB + t] = acc * sNorm;
}

// ---------------------------------------------------------------- launch
extern "C" void kernel_launch(void* const* d_in, const int* in_sizes, int n_in,
                              void* d_out, int out_size, void* d_ws, size_t ws_size,
                              hipStream_t stream) {
    const float* x = (const float*)d_in[0];
    const float* W = (const float*)d_in[1];
    float* out = (float*)d_out;

    char* ws = (char*)d_ws;
    _Float16* G = (_Float16*)ws;                                   // 16 MB
    size_t goff = (size_t)B * D * D * sizeof(_Float16);
    float* gvec   = (float*)(ws + goff);
    float* pooled = gvec + (size_t)B * D;
    float* psum   = pooled + (size_t)B * D;                        // B*16*512 floats (1 MB)
    size_t qoff = goff + (2 * (size_t)B * D + (size_t)B * 16 * D) * sizeof(float);
    qoff = (qoff + 255) & ~(size_t)255;

    size_t per_batch_q = (size_t)D * NPTS * sizeof(short);         // 1 MB
    size_t avail = ws_size > qoff ? ws_size - qoff : 0;
    int CH = (int)(avail / (2 * per_batch_q));
    if (CH > B) CH = B;
    if (CH < 1) CH = 1;
    short* Qh = (short*)(ws + qoff);
    short* Ql = (short*)(ws + qoff + (size_t)CH * per_batch_q);

    for (int c0 = 0; c0 < B; c0 += CH) {
        int nb = (B - c0 < CH) ? (B - c0) : CH;
        prep_kernel<<<dim3(16, 8, nb), 256, 0, stream>>>(x + (size_t)c0 * NPTS * D,
                                                         Qh, Ql, psum, c0);
        syrk_kernel<<<dim3(10, nb), 256, 0, stream>>>(Qh, Ql, G + (size_t)c0 * D * D);
    }
    colsum_reduce<<<dim3(B), 256, 0, stream>>>(psum, gvec);
    cg_kernel<<<dim3(B), 1024, 0, stream>>>(G, gvec, pooled);
    outproj_kernel<<<dim3(B), 512, 0, stream>>>(pooled, W, out);
}

// Round 4
// 162.626 us; speedup vs baseline: 3.5530x; 1.3438x over previous
//
#include <hip/hip_runtime.h>
#include <math.h>
#include <stdint.h>

// x (32,32,32,512) fp32, W (512,512) fp32. b=32, n=1024, d=512, emb=512, lambda=1.
// pooled = (P^T P + I)^-1 (P^T 1)  [push-through identity]
// Round 4: single-pass fp16 MFMA syrk (no hi/lo split), NITER 16, colsum fused
// into cg prologue, two-stage outproj (256-way parallel W read).

#define B    32
#define NPTS 1024
#define D    512
#define EMB  512
#define NITER 16

typedef __attribute__((ext_vector_type(8))) short short8;
typedef __attribute__((ext_vector_type(4))) float f32x4;
typedef __attribute__((ext_vector_type(8))) _Float16 h16x8;
typedef __attribute__((ext_vector_type(4))) _Float16 h16x4;

#define MFMA16F(a, b, c) __builtin_amdgcn_mfma_f32_16x16x32_f16(a, b, c, 0, 0, 0)

__device__ __forceinline__ void gload16(const void* g, void* lds_wave_base) {
    __builtin_amdgcn_global_load_lds(
        (const __attribute__((address_space(1))) void*)g,
        (__attribute__((address_space(3))) void*)lds_wave_base, 16, 0, 0);
}

// ---------------------------------------------------------------- prep: x(b,n,d) -> Q (b,d,n) fp16 + colsum partials
__global__ __launch_bounds__(256) void prep_kernel(const float* __restrict__ x,
                                                   short* __restrict__ Qh,
                                                   float* __restrict__ psum,
                                                   int b0) {
    int n0 = blockIdx.x * 64, d0 = blockIdx.y * 64, bl = blockIdx.z;
    const float* xb = x + (size_t)bl * NPTS * D;
    __shared__ float tile[64][65];
    __shared__ float cs[4][64];
    int t = threadIdx.x;
    int lrow = t >> 4, lc4 = (t & 15) * 4;
    #pragma unroll
    for (int r = 0; r < 4; ++r) {
        int row = lrow + r * 16;
        const float* src = xb + (size_t)(n0 + row) * D + d0 + lc4;
        tile[row][lc4 + 0] = src[0];
        tile[row][lc4 + 1] = src[1];
        tile[row][lc4 + 2] = src[2];
        tile[row][lc4 + 3] = src[3];
    }
    __syncthreads();

    // column partial sums (colsum fusion)
    {
        int col = t & 63, grp = t >> 6;
        float s = 0.f;
        #pragma unroll
        for (int r = 0; r < 16; ++r) s += tile[grp * 16 + r][col];
        cs[grp][col] = s;
    }
    __syncthreads();
    if (t < 64)
        psum[((size_t)(b0 + bl) * 16 + blockIdx.x) * D + d0 + t] =
            cs[0][t] + cs[1][t] + cs[2][t] + cs[3][t];

    // transposed fp16 pack
    int drow = t >> 2, nseg = (t & 3) * 16;
    size_t obase = (size_t)bl * D * NPTS + (size_t)(d0 + drow) * NPTS + n0 + nseg;
    short8 h0, h1;
    #pragma unroll
    for (int k = 0; k < 8; ++k) {
        _Float16 hv = (_Float16)tile[nseg + k][drow];
        h0[k] = __builtin_bit_cast(short, hv);
    }
    #pragma unroll
    for (int k = 0; k < 8; ++k) {
        _Float16 hv = (_Float16)tile[nseg + 8 + k][drow];
        h1[k] = __builtin_bit_cast(short, hv);
    }
    *(short8*)(Qh + obase)     = h0;
    *(short8*)(Qh + obase + 8) = h1;
}

// ---------------------------------------------------------------- syrk: G = Q Q^T (fp16 MFMA), upper 128x128 tiles + mirror, fp16 out
__global__ __launch_bounds__(256) void syrk_kernel(const short* __restrict__ Qh,
                                                   _Float16* __restrict__ G) {
    int bx = blockIdx.x, bl = blockIdx.y;
    int i = 0, rem = bx;
    #pragma unroll
    for (int ii = 0; ii < 4; ++ii) {
        int c = 4 - ii;
        if (rem < c) { i = ii; break; }
        rem -= c;
    }
    int j = i + rem;
    int i0 = i * 128, j0 = j * 128;

    const short* Qhb = Qh + (size_t)bl * D * NPTS;
    _Float16* Gb = G + (size_t)bl * D * D;

    __shared__ short smem[2 * 4096];   // A, B: [128][32] fp16 each (8KB)
    char* smb = (char*)smem;

    int t = threadIdx.x;
    int lane = t & 63, wid = t >> 6;
    int wm = wid >> 1, wn = wid & 1;

    f32x4 acc[4][4];
    f32x4 zero = {0.f, 0.f, 0.f, 0.f};
    #pragma unroll
    for (int a = 0; a < 4; ++a)
        #pragma unroll
        for (int c = 0; c < 4; ++c) acc[a][c] = zero;

    for (int kt = 0; kt < NPTS / 32; ++kt) {
        int ks = kt * 32;
        #pragma unroll
        for (int q = 0; q < 2; ++q) {
            int off = q * 4096 + wid * 1024 + lane * 16;   // bytes within 8KB tile
            int row = off >> 6, inb = off & 63;
            int ldsoff = q * 4096 + wid * 1024;            // wave-uniform
            const char* sA = (const char*)(Qhb + (size_t)(i0 + row) * NPTS + ks) + inb;
            const char* sB = (const char*)(Qhb + (size_t)(j0 + row) * NPTS + ks) + inb;
            gload16(sA, smb + ldsoff);
            gload16(sB, smb + 8192 + ldsoff);
        }
        __syncthreads();

        short8 ah[4], bh[4];
        int mrow = lane & 15;
        int kb = (lane >> 4) * 8;
        #pragma unroll
        for (int f = 0; f < 4; ++f) {
            int ra = (wm * 64 + f * 16 + mrow) * 32 + kb;
            int rb = (wn * 64 + f * 16 + mrow) * 32 + kb;
            ah[f] = *(const short8*)(smem + ra);
            bh[f] = *(const short8*)(smem + 4096 + rb);
        }
        #pragma unroll
        for (int fm = 0; fm < 4; ++fm)
            #pragma unroll
            for (int fn = 0; fn < 4; ++fn)
                acc[fm][fn] = MFMA16F(__builtin_bit_cast(h16x8, ah[fm]),
                                      __builtin_bit_cast(h16x8, bh[fn]),
                                      acc[fm][fn]);
        __syncthreads();
    }

    // C/D layout: col = lane&15, row = (lane>>4)*4 + reg
    int crow0 = i0 + wm * 64 + (lane >> 4) * 4;
    int ccol0 = j0 + wn * 64 + (lane & 15);
    #pragma unroll
    for (int fm = 0; fm < 4; ++fm)
        #pragma unroll
        for (int fn = 0; fn < 4; ++fn)
            #pragma unroll
            for (int r = 0; r < 4; ++r)
                Gb[(size_t)(crow0 + fm * 16 + r) * D + (ccol0 + fn * 16)] =
                    (_Float16)acc[fm][fn][r];
    if (i != j) {
        #pragma unroll
        for (int fm = 0; fm < 4; ++fm)
            #pragma unroll
            for (int fn = 0; fn < 4; ++fn) {
                h16x4 v = {(_Float16)acc[fm][fn][0], (_Float16)acc[fm][fn][1],
                           (_Float16)acc[fm][fn][2], (_Float16)acc[fm][fn][3]};
                *(h16x4*)&Gb[(size_t)(ccol0 + fn * 16) * D + (crow0 + fm * 16)] = v;
            }
    }
}

// ---------------------------------------------------------------- CG solve (G+I) pooled = g, fp16 G, colsum fused
__device__ __forceinline__ float block_reduce(float v, float* red, int nwaves) {
    #pragma unroll
    for (int o = 32; o > 0; o >>= 1) v += __shfl_down(v, o);
    int wid = threadIdx.x >> 6, lane = threadIdx.x & 63;
    __syncthreads();
    if (lane == 0) red[wid] = v;
    __syncthreads();
    float s = 0.f;
    if ((int)threadIdx.x < nwaves) {
        s = red[threadIdx.x];
        #pragma unroll
        for (int o = 8; o > 0; o >>= 1) s += __shfl_down(s, o);
    }
    return s;   // valid in thread 0
}

__global__ __launch_bounds__(1024) void cg_kernel(const _Float16* __restrict__ G,
                                                  const float* __restrict__ psum,
                                                  float* __restrict__ pooled) {
    int b = blockIdx.x;
    const _Float16* Gb = G + (size_t)b * D * D;

    __shared__ float partf[16 * 512];      // 32 KB
    __shared__ float xv[D], rv[D], pv[D], yv[D];
    __shared__ float red[16];
    __shared__ float sAlpha, sBeta, sRR;

    int t = threadIdx.x;
    float ge = 0.f;
    if (t < D) {
        #pragma unroll
        for (int i = 0; i < 16; ++i) ge += psum[((size_t)b * 16 + i) * D + t];
        xv[t] = 0.f; rv[t] = ge; pv[t] = ge;
    }

    float rr0 = block_reduce(ge * ge, red, 16);
    if (t == 0) sRR = rr0;
    __syncthreads();
    float rr = sRR;

    int ecol = (t & 63) * 8;               // 8 outputs per thread
    int cgrp = t >> 6;                     // 16 c-groups of 32
    const _Float16* gp = Gb + (size_t)(cgrp * 32) * D + ecol;

    for (int it = 0; it < NITER; ++it) {
        // y = (G+I)p
        float acc[8] = {0.f, 0.f, 0.f, 0.f, 0.f, 0.f, 0.f, 0.f};
        #pragma unroll 16
        for (int c = 0; c < 32; ++c) {
            float pc = pv[cgrp * 32 + c];
            h16x8 q = *(const h16x8*)(gp + (size_t)c * D);
            #pragma unroll
            for (int k = 0; k < 8; ++k)
                acc[k] = fmaf((float)q[k], pc, acc[k]);
        }
        f32x4 a0 = {acc[0], acc[1], acc[2], acc[3]};
        f32x4 a1 = {acc[4], acc[5], acc[6], acc[7]};
        *(f32x4*)(partf + cgrp * 512 + ecol)     = a0;
        *(f32x4*)(partf + cgrp * 512 + ecol + 4) = a1;
        __syncthreads();

        float pyp = 0.f;
        if (t < D) {
            float y = pv[t];
            #pragma unroll
            for (int g = 0; g < 16; ++g) y += partf[g * 512 + t];
            yv[t] = y;
            pyp = pv[t] * y;
        }
        float py = block_reduce(pyp, red, 16);
        if (t == 0) sAlpha = rr / fmaxf(py, 1e-30f);
        __syncthreads();
        float alpha = sAlpha;

        float rn2 = 0.f;
        if (t < D) {
            xv[t] += alpha * pv[t];
            float rn = rv[t] - alpha * yv[t];
            rv[t] = rn;
            rn2 = rn * rn;
        }
        float rrn = block_reduce(rn2, red, 16);
        if (t == 0) { sBeta = rrn / fmaxf(rr, 1e-30f); sRR = rrn; }
        __syncthreads();
        float beta = sBeta;
        rr = sRR;
        if (t < D) pv[t] = rv[t] + beta * pv[t];
        __syncthreads();
    }

    if (t < D) pooled[b * D + t] = xv[t];
}

// ---------------------------------------------------------------- outproj stage 1: proj = pooled @ W (e-tiled), sq partials
__global__ __launch_bounds__(256) void outproj1_kernel(const float* __restrict__ pooled,
                                                       const float* __restrict__ W,
                                                       float* __restrict__ proj,
                                                       float* __restrict__ sqpart) {
    int b = blockIdx.x, et = blockIdx.y;
    int t = threadIdx.x;
    int e = et * 64 + (t & 63);
    int dseg = t >> 6;                       // 4 segs x 128 d
    __shared__ float pl[D];
    __shared__ float part[4][64];
    if (t < D / 2) {
        pl[t * 2]     = pooled[b * D + t * 2];
        pl[t * 2 + 1] = pooled[b * D + t * 2 + 1];
    }
    __syncthreads();
    float acc = 0.f;
    #pragma unroll 8
    for (int k = 0; k < 128; ++k)
        acc = fmaf(pl[dseg * 128 + k], W[(size_t)(dseg * 128 + k) * EMB + e], acc);
    part[dseg][t & 63] = acc;
    __syncthreads();
    if (t < 64) {
        float y = part[0][t] + part[1][t] + part[2][t] + part[3][t];
        proj[(size_t)b * EMB + et * 64 + t] = y;
        float sq = y * y;
        #pragma unroll
        for (int o = 32; o > 0; o >>= 1) sq += __shfl_down(sq, o);
        if (t == 0) sqpart[b * 8 + et] = sq;
    }
}

// ---------------------------------------------------------------- outproj stage 2: normalize
__global__ __launch_bounds__(512) void outproj2_kernel(const float* __restrict__ proj,
                                                       const float* __restrict__ sqpart,
                                                       float* __restrict__ out) {
    int b = blockIdx.x, t = threadIdx.x;
    float ss = 0.f;
    #pragma unroll
    for (int i = 0; i < 8; ++i) ss += sqpart[b * 8 + i];
    float s = rsqrtf(fmaxf(ss, 1e-12f));
    out[(size_t)b * EMB + t] = proj[(size_t)b * EMB + t] * s;
}

// ---------------------------------------------------------------- launch
extern "C" void kernel_launch(void* const* d_in, const int* in_sizes, int n_in,
                              void* d_out, int out_size, void* d_ws, size_t ws_size,
                              hipStream_t stream) {
    const float* x = (const float*)d_in[0];
    const float* W = (const float*)d_in[1];
    float* out = (float*)d_out;

    char* ws = (char*)d_ws;
    _Float16* G = (_Float16*)ws;                                   // 16 MB
    size_t off = (size_t)B * D * D * sizeof(_Float16);
    float* psum   = (float*)(ws + off); off += (size_t)B * 16 * D * sizeof(float);
    float* pooled = (float*)(ws + off); off += (size_t)B * D * sizeof(float);
    float* proj   = (float*)(ws + off); off += (size_t)B * EMB * sizeof(float);
    float* sqpart = (float*)(ws + off); off += (size_t)B * 8 * sizeof(float);
    off = (off + 255) & ~(size_t)255;

    size_t per_batch_q = (size_t)D * NPTS * sizeof(short);         // 1 MB fp16
    size_t avail = ws_size > off ? ws_size - off : 0;
    int CH = (int)(avail / per_batch_q);
    if (CH > B) CH = B;
    if (CH < 1) CH = 1;
    short* Qh = (short*)(ws + off);

    for (int c0 = 0; c0 < B; c0 += CH) {
        int nb = (B - c0 < CH) ? (B - c0) : CH;
        prep_kernel<<<dim3(16, 8, nb), 256, 0, stream>>>(x + (size_t)c0 * NPTS * D,
                                                         Qh, psum, c0);
        syrk_kernel<<<dim3(10, nb), 256, 0, stream>>>(Qh, G + (size_t)c0 * D * D);
    }
    cg_kernel<<<dim3(B), 1024, 0, stream>>>(G, psum, pooled);
    outproj1_kernel<<<dim3(B, 8), 256, 0, stream>>>(pooled, W, proj, sqpart);
    outproj2_kernel<<<dim3(B), 512, 0, stream>>>(proj, sqpart, out);
}